// Round 1
// baseline (2086.504 us; speedup 1.0000x reference)
//
#include <hip/hip_runtime.h>

// Conv1D dequant-GEMM: y[M,N] = x[M,K] @ (w_q[K,N]*scale[N]) + bias[N]
// M=8192 (B*S), K=4096, N=16384. fp32 I/O, int8-valued int32 weights.
// Plan: bf16 MFMA (w_q exact in bf16; scale/bias applied in fp32 epilogue).

#define M_DIM 8192
#define K_DIM 4096
#define N_DIM 16384

typedef unsigned short u16;
typedef __attribute__((ext_vector_type(8))) short short8;   // 8 x bf16 bits (4 VGPR)
typedef __attribute__((ext_vector_type(4))) float floatx4;  // MFMA acc

__device__ __forceinline__ u16 f2bf(float f) {
    // round-to-nearest-even fp32 -> bf16 (no NaN handling needed here)
    unsigned int u = __builtin_bit_cast(unsigned int, f);
    u += 0x7fffu + ((u >> 16) & 1u);
    return (u16)(u >> 16);
}

// ---------------- prep 1: x fp32 -> bf16 ----------------
__global__ __launch_bounds__(256) void cvt_x_kernel(const float4* __restrict__ x,
                                                    uint4* __restrict__ out) {
    int i = blockIdx.x * 256 + threadIdx.x;   // one uint4 = 8 bf16 per thread
    float4 a = x[2 * i];
    float4 b = x[2 * i + 1];
    uint4 o;
    o.x = (unsigned)f2bf(a.x) | ((unsigned)f2bf(a.y) << 16);
    o.y = (unsigned)f2bf(a.z) | ((unsigned)f2bf(a.w) << 16);
    o.z = (unsigned)f2bf(b.x) | ((unsigned)f2bf(b.y) << 16);
    o.w = (unsigned)f2bf(b.z) | ((unsigned)f2bf(b.w) << 16);
    out[i] = o;
}

// ---------------- prep 2: w_q[K,N] int32 -> wT[N,K] bf16 (tiled transpose) ----
__global__ __launch_bounds__(256) void transpose_wq(const int* __restrict__ wq,
                                                    u16* __restrict__ wT) {
    __shared__ u16 tile[64][65];  // +1 pad breaks bank aliasing on column reads
    const int n0 = blockIdx.x * 64;
    const int k0 = blockIdx.y * 64;
    const int tx = threadIdx.x;   // 0..15
    const int ty = threadIdx.y;   // 0..15

    // load: rows = k, 4 consecutive n per thread via int4 (coalesced 16B)
    #pragma unroll
    for (int r = 0; r < 4; ++r) {
        int kl = ty + 16 * r;
        const int4 v = *(const int4*)(wq + (size_t)(k0 + kl) * N_DIM + n0 + tx * 4);
        tile[kl][tx * 4 + 0] = f2bf((float)v.x);
        tile[kl][tx * 4 + 1] = f2bf((float)v.y);
        tile[kl][tx * 4 + 2] = f2bf((float)v.z);
        tile[kl][tx * 4 + 3] = f2bf((float)v.w);
    }
    __syncthreads();
    // store: rows = n, 4 consecutive k per thread (8B coalesced)
    #pragma unroll
    for (int r = 0; r < 4; ++r) {
        int nl = ty + 16 * r;
        ushort4 o;
        o.x = tile[tx * 4 + 0][nl];
        o.y = tile[tx * 4 + 1][nl];
        o.z = tile[tx * 4 + 2][nl];
        o.w = tile[tx * 4 + 3][nl];
        *(ushort4*)(wT + (size_t)(n0 + nl) * K_DIM + k0 + tx * 4) = o;
    }
}

// ---------------- async global->LDS 16B ----------------
__device__ __forceinline__ void async_copy16(const u16* gptr, u16* ldsptr) {
    __builtin_amdgcn_global_load_lds(
        (const __attribute__((address_space(1))) void*)gptr,
        (__attribute__((address_space(3))) void*)ldsptr,
        16, 0, 0);
}

// ---------------- main GEMM: C = A(bf16)[M,K] * Bt(bf16)[N,K]^T, fused scale/bias
__global__ __launch_bounds__(256) void gemm_bf16(const u16* __restrict__ A,
                                                 const u16* __restrict__ Bt,
                                                 const float* __restrict__ scale,
                                                 const float* __restrict__ bias,
                                                 float* __restrict__ C) {
    __shared__ u16 As[128 * 32];  // [row_m][k], 8 KiB, no pad (global_load_lds)
    __shared__ u16 Bs[128 * 32];  // [row_n][k]

    const int tid  = threadIdx.x;
    const int lane = tid & 63;
    const int wave = tid >> 6;
    const int m0 = blockIdx.y * 128;
    const int n0 = blockIdx.x * 128;
    const int wm = (wave & 1) * 64;   // wave's 64x64 quadrant
    const int wn = (wave >> 1) * 64;

    floatx4 acc[4][4];
    #pragma unroll
    for (int i = 0; i < 4; ++i)
        #pragma unroll
        for (int j = 0; j < 4; ++j)
            acc[i][j] = (floatx4){0.f, 0.f, 0.f, 0.f};

    // staging: thread t covers row = t/4, k-chunk = (t%4)*8 -> LDS offset t*16B
    const int srow = tid >> 2;
    const int skoff = (tid & 3) * 8;
    // fragment read coords
    const int fr   = lane & 15;
    const int quad = lane >> 4;

    for (int kt = 0; kt < K_DIM; kt += 32) {
        __syncthreads();  // previous tile fully consumed
        #pragma unroll
        for (int j = 0; j < 2; ++j) {
            int row = srow + j * 64;
            async_copy16(A  + (size_t)(m0 + row) * K_DIM + kt + skoff,
                         As + row * 32 + skoff);
            async_copy16(Bt + (size_t)(n0 + row) * K_DIM + kt + skoff,
                         Bs + row * 32 + skoff);
        }
        __syncthreads();  // staged (compiler drains vmcnt before barrier)

        short8 af[4], bfv[4];
        #pragma unroll
        for (int i = 0; i < 4; ++i)
            af[i] = *(const short8*)(As + (wm + i * 16 + fr) * 32 + quad * 8);
        #pragma unroll
        for (int j = 0; j < 4; ++j)
            bfv[j] = *(const short8*)(Bs + (wn + j * 16 + fr) * 32 + quad * 8);

        #pragma unroll
        for (int i = 0; i < 4; ++i)
            #pragma unroll
            for (int j = 0; j < 4; ++j)
                acc[i][j] = __builtin_amdgcn_mfma_f32_16x16x32_bf16(
                    af[i], bfv[j], acc[i][j], 0, 0, 0);
    }

    // epilogue: y = acc*scale[col] + bias[col]; C/D map col=lane&15, row=quad*4+r
    #pragma unroll
    for (int j = 0; j < 4; ++j) {
        const int col = n0 + wn + j * 16 + fr;
        const float s = scale[col];
        const float b = bias[col];
        #pragma unroll
        for (int i = 0; i < 4; ++i) {
            const int rowb = m0 + wm + i * 16 + quad * 4;
            #pragma unroll
            for (int r = 0; r < 4; ++r)
                C[(size_t)(rowb + r) * N_DIM + col] = acc[i][j][r] * s + b;
        }
    }
}

extern "C" void kernel_launch(void* const* d_in, const int* in_sizes, int n_in,
                              void* d_out, int out_size, void* d_ws, size_t ws_size,
                              hipStream_t stream) {
    const float* x     = (const float*)d_in[0];
    const int*   wq    = (const int*)d_in[1];
    const float* scale = (const float*)d_in[2];
    const float* bias  = (const float*)d_in[3];
    float* y = (float*)d_out;

    u16* wT = (u16*)d_ws;                                        // 128 MiB
    u16* xb = (u16*)((char*)d_ws + (size_t)N_DIM * K_DIM * 2);   // +64 MiB

    cvt_x_kernel<<<(M_DIM * (size_t)K_DIM) / (256 * 8), 256, 0, stream>>>(
        (const float4*)x, (uint4*)xb);
    transpose_wq<<<dim3(N_DIM / 64, K_DIM / 64), dim3(16, 16), 0, stream>>>(wq, wT);
    gemm_bf16<<<dim3(N_DIM / 128, M_DIM / 128), 256, 0, stream>>>(
        xb, wT, scale, bias, y);
}